// Round 1
// 644.348 us; speedup vs baseline: 1.0492x; 1.0492x over previous
//
#include <hip/hip_runtime.h>
#include <hip/hip_bf16.h>
#include <math.h>

#define N_NODES 100000
#define N_EDGES 500000
#define M0 8.0f
#define INV_SQRT32 0.17677669529663687f
#define NB_SCAN 98   // ceil(100000/1024)

typedef __attribute__((ext_vector_type(8))) short bf16x8;
typedef __attribute__((ext_vector_type(4))) float f32x4;
typedef __attribute__((ext_vector_type(8))) unsigned short us8;

static __device__ __forceinline__ unsigned short f2bf(float f) {
    __hip_bfloat16 h = __float2bfloat16(f);
    return *(unsigned short*)&h;
}

// ---------------------------------------------------------------------------
// prep_w: split all weights into bf16 hi/lo pairs (Markidis). One-shot, tiny.
// WB: [4][128][128] (Wq,Wk,Wv,Ws), WE: [128][64].
// ---------------------------------------------------------------------------
__global__ __launch_bounds__(256) void prep_w_kernel(
    const float* __restrict__ Wq, const float* __restrict__ Wk,
    const float* __restrict__ Wv, const float* __restrict__ Ws,
    const float* __restrict__ We,
    unsigned short* __restrict__ WBh, unsigned short* __restrict__ WBl,
    unsigned short* __restrict__ WEh, unsigned short* __restrict__ WEl)
{
    const int i = blockIdx.x * 256 + threadIdx.x;
    float v;
    unsigned short *ph, *pl;
    int idx;
    if (i < 65536) {
        const int p = i >> 14;
        const float* W = (p == 0) ? Wq : (p == 1) ? Wk : (p == 2) ? Wv : Ws;
        v = W[i & 16383];
        ph = WBh; pl = WBl; idx = i;
    } else if (i < 73728) {
        idx = i - 65536;
        v = We[idx];
        ph = WEh; pl = WEl;
    } else {
        return;
    }
    const unsigned short h = f2bf(v);
    ph[idx] = h;
    pl[idx] = f2bf(v - __uint_as_float((unsigned)h << 16));
}

// ---------------------------------------------------------------------------
// K1: fused node projection via MFMA, 3-product bf16 split (~fp32 accuracy).
// One pass over x (read once, not 4x). Block = 256 thr = 4 waves.
// Tile: 64 rows x 128 cols per projection; 4 projections sequential.
// LDS: x hi/lo [64][128] (32KB) + W-chunk hi/lo [128][64] (32KB) = 64KB.
// XOR swizzle (k ^= (row&7)<<3 in ushorts) -> conflict-free ds_read_b128.
// ---------------------------------------------------------------------------
__global__ __launch_bounds__(256) void node_proj_mfma(
    const float* __restrict__ x,
    const unsigned short* __restrict__ WBh, const unsigned short* __restrict__ WBl,
    const float* __restrict__ bq, const float* __restrict__ bk,
    const float* __restrict__ bv, const float* __restrict__ bs,
    float* __restrict__ Qn, float* __restrict__ Kn, float* __restrict__ Vn,
    float* __restrict__ out)
{
    __shared__ __align__(16) unsigned short xh[64 * 128];
    __shared__ __align__(16) unsigned short xl[64 * 128];
    __shared__ __align__(16) unsigned short wh[128 * 64];
    __shared__ __align__(16) unsigned short wl[128 * 64];

    const int t = threadIdx.x;
    const long r0 = (long)blockIdx.x * 64;
    const int lane = t & 63;
    const int wid = t >> 6;          // wave id: owns cols wid*32..wid*32+31
    const int fr = lane & 15;
    const int fq = lane >> 4;

    // stage x tile [64 rows][128 k] -> hi/lo bf16, swizzled
    for (int i = t; i < 64 * 32; i += 256) {
        const int r = i >> 5;
        const int s = i & 31;                 // float4 slot; k = s*4
        const long row = r0 + r;
        float4 v = (row < N_NODES) ? *(const float4*)&x[row * 128 + s * 4]
                                   : make_float4(0.f, 0.f, 0.f, 0.f);
        const unsigned short h0 = f2bf(v.x), h1 = f2bf(v.y),
                             h2 = f2bf(v.z), h3 = f2bf(v.w);
        ushort4 hv, lv;
        hv.x = h0; hv.y = h1; hv.z = h2; hv.w = h3;
        lv.x = f2bf(v.x - __uint_as_float((unsigned)h0 << 16));
        lv.y = f2bf(v.y - __uint_as_float((unsigned)h1 << 16));
        lv.z = f2bf(v.z - __uint_as_float((unsigned)h2 << 16));
        lv.w = f2bf(v.w - __uint_as_float((unsigned)h3 << 16));
        const int di = r * 128 + ((s * 4) ^ ((r & 7) << 3));
        *(ushort4*)&xh[di] = hv;
        *(ushort4*)&xl[di] = lv;
    }

    for (int p = 0; p < 4; ++p) {
        const float* bias = (p == 0) ? bq : (p == 1) ? bk : (p == 2) ? bv : bs;
        float* dst        = (p == 0) ? Qn : (p == 1) ? Kn : (p == 2) ? Vn : out;

        f32x4 acc[4][2];
#pragma unroll
        for (int m = 0; m < 4; ++m)
#pragma unroll
            for (int n = 0; n < 2; ++n) acc[m][n] = (f32x4){0.f, 0.f, 0.f, 0.f};

        for (int kc = 0; kc < 2; ++kc) {
            __syncthreads();   // previous chunk's MFMA reads done (or x stage visible)
            // stage W chunk [128 ch][64 k] from pre-split bf16
            for (int i = t; i < 1024; i += 256) {
                const int r = i >> 3;
                const int s = i & 7;          // 8-ushort slot; k = s*8
                const int gi = p * 16384 + r * 128 + kc * 64 + s * 8;
                const int di = r * 64 + ((s * 8) ^ ((r & 7) << 3));
                *(us8*)&wh[di] = *(const us8*)&WBh[gi];
                *(us8*)&wl[di] = *(const us8*)&WBl[gi];
            }
            __syncthreads();

#pragma unroll
            for (int ks = 0; ks < 2; ++ks) {
                const int kx = kc * 64 + ks * 32 + fq * 8;  // k idx in x tile
                const int kw = ks * 32 + fq * 8;            // k idx in W chunk
                bf16x8 ah[4], al[4], bh[2], bl[2];
#pragma unroll
                for (int m = 0; m < 4; ++m) {
                    const int r = m * 16 + fr;
                    const int di = r * 128 + (kx ^ ((r & 7) << 3));
                    ah[m] = *(const bf16x8*)&xh[di];
                    al[m] = *(const bf16x8*)&xl[di];
                }
#pragma unroll
                for (int n = 0; n < 2; ++n) {
                    const int r = wid * 32 + n * 16 + fr;
                    const int di = r * 64 + (kw ^ ((r & 7) << 3));
                    bh[n] = *(const bf16x8*)&wh[di];
                    bl[n] = *(const bf16x8*)&wl[di];
                }
#pragma unroll
                for (int m = 0; m < 4; ++m)
#pragma unroll
                    for (int n = 0; n < 2; ++n) {
                        acc[m][n] = __builtin_amdgcn_mfma_f32_16x16x32_bf16(
                            ah[m], bh[n], acc[m][n], 0, 0, 0);
                        acc[m][n] = __builtin_amdgcn_mfma_f32_16x16x32_bf16(
                            ah[m], bl[n], acc[m][n], 0, 0, 0);
                        acc[m][n] = __builtin_amdgcn_mfma_f32_16x16x32_bf16(
                            al[m], bh[n], acc[m][n], 0, 0, 0);
                    }
            }
        }

        // epilogue: C/D layout col=lane&15, row=(lane>>4)*4+j
        float bb[2];
#pragma unroll
        for (int n = 0; n < 2; ++n) bb[n] = bias[wid * 32 + n * 16 + fr];
#pragma unroll
        for (int m = 0; m < 4; ++m) {
            const long rowb = r0 + m * 16 + fq * 4;
#pragma unroll
            for (int j = 0; j < 4; ++j) {
                if (rowb + j < N_NODES) {
#pragma unroll
                    for (int n = 0; n < 2; ++n)
                        dst[(rowb + j) * 128 + wid * 32 + n * 16 + fr] =
                            acc[m][n][j] + bb[n];
                }
            }
        }
    }
}

// ---------------------------------------------------------------------------
// K1b: Ee = ea @ We^T via MFMA, 3-product split, bf16 out.
// Block tile 128x128, K=64 fully resident. 4 waves in 2x2.
// ---------------------------------------------------------------------------
__global__ __launch_bounds__(256) void ee_gemm_mfma(
    const float* __restrict__ ea,
    const unsigned short* __restrict__ WEh, const unsigned short* __restrict__ WEl,
    unsigned short* __restrict__ Ee)
{
    __shared__ __align__(16) unsigned short eh[128 * 64];
    __shared__ __align__(16) unsigned short el[128 * 64];
    __shared__ __align__(16) unsigned short wh[128 * 64];
    __shared__ __align__(16) unsigned short wl[128 * 64];

    const int t = threadIdx.x;
    const long e0 = (long)blockIdx.x * 128;
    const int lane = t & 63;
    const int wr = (t >> 6) >> 1;    // wave row block: rows wr*64
    const int wc = (t >> 6) & 1;     // wave col block: cols wc*64
    const int fr = lane & 15;
    const int fq = lane >> 4;

    // stage We [128][64] hi/lo (pre-split)
    for (int i = t; i < 1024; i += 256) {
        const int r = i >> 3;
        const int s = i & 7;
        const int di = r * 64 + ((s * 8) ^ ((r & 7) << 3));
        *(us8*)&wh[di] = *(const us8*)&WEh[r * 64 + s * 8];
        *(us8*)&wl[di] = *(const us8*)&WEl[r * 64 + s * 8];
    }
    // stage ea tile [128][64] -> hi/lo
    for (int i = t; i < 128 * 16; i += 256) {
        const int r = i >> 4;
        const int s = i & 15;                 // k = s*4
        const long e = e0 + r;
        float4 v = (e < N_EDGES) ? *(const float4*)&ea[e * 64 + s * 4]
                                 : make_float4(0.f, 0.f, 0.f, 0.f);
        const unsigned short h0 = f2bf(v.x), h1 = f2bf(v.y),
                             h2 = f2bf(v.z), h3 = f2bf(v.w);
        ushort4 hv, lv;
        hv.x = h0; hv.y = h1; hv.z = h2; hv.w = h3;
        lv.x = f2bf(v.x - __uint_as_float((unsigned)h0 << 16));
        lv.y = f2bf(v.y - __uint_as_float((unsigned)h1 << 16));
        lv.z = f2bf(v.z - __uint_as_float((unsigned)h2 << 16));
        lv.w = f2bf(v.w - __uint_as_float((unsigned)h3 << 16));
        const int di = r * 64 + ((s * 4) ^ ((r & 7) << 3));
        *(ushort4*)&eh[di] = hv;
        *(ushort4*)&el[di] = lv;
    }
    __syncthreads();

    f32x4 acc[4][4];
#pragma unroll
    for (int m = 0; m < 4; ++m)
#pragma unroll
        for (int n = 0; n < 4; ++n) acc[m][n] = (f32x4){0.f, 0.f, 0.f, 0.f};

#pragma unroll
    for (int ks = 0; ks < 2; ++ks) {
        const int kk = ks * 32 + fq * 8;
        bf16x8 ah[4], al[4], bh[4], bl[4];
#pragma unroll
        for (int m = 0; m < 4; ++m) {
            const int r = wr * 64 + m * 16 + fr;
            const int di = r * 64 + (kk ^ ((r & 7) << 3));
            ah[m] = *(const bf16x8*)&eh[di];
            al[m] = *(const bf16x8*)&el[di];
        }
#pragma unroll
        for (int n = 0; n < 4; ++n) {
            const int r = wc * 64 + n * 16 + fr;
            const int di = r * 64 + (kk ^ ((r & 7) << 3));
            bh[n] = *(const bf16x8*)&wh[di];
            bl[n] = *(const bf16x8*)&wl[di];
        }
#pragma unroll
        for (int m = 0; m < 4; ++m)
#pragma unroll
            for (int n = 0; n < 4; ++n) {
                acc[m][n] = __builtin_amdgcn_mfma_f32_16x16x32_bf16(
                    ah[m], bh[n], acc[m][n], 0, 0, 0);
                acc[m][n] = __builtin_amdgcn_mfma_f32_16x16x32_bf16(
                    ah[m], bl[n], acc[m][n], 0, 0, 0);
                acc[m][n] = __builtin_amdgcn_mfma_f32_16x16x32_bf16(
                    al[m], bh[n], acc[m][n], 0, 0, 0);
            }
    }

#pragma unroll
    for (int m = 0; m < 4; ++m) {
        const long erow = e0 + wr * 64 + m * 16 + fq * 4;
#pragma unroll
        for (int j = 0; j < 4; ++j) {
            if (erow + j < N_EDGES) {
#pragma unroll
                for (int n = 0; n < 4; ++n)
                    Ee[(erow + j) * 128 + wc * 64 + n * 16 + fr] =
                        f2bf(acc[m][n][j]);
            }
        }
    }
}

// ---------------------------------------------------------------------------
// CSR build: histogram -> 2-level exclusive scan -> fill. Unchanged.
// ---------------------------------------------------------------------------
__global__ __launch_bounds__(256) void csr_hist_kernel(
    const int* __restrict__ ei, int* __restrict__ cursor)
{
    const int e = blockIdx.x * 256 + threadIdx.x;
    if (e >= N_EDGES) return;
    atomicAdd(&cursor[ei[N_EDGES + e]], 1);
}

__global__ __launch_bounds__(256) void csr_scan_part_kernel(
    const int* __restrict__ deg, int* __restrict__ bsum)
{
    __shared__ int red[256];
    const int t = threadIdx.x;
    const int i0 = blockIdx.x * 1024 + t * 4;
    int s = 0;
#pragma unroll
    for (int j = 0; j < 4; ++j) {
        const int n = i0 + j;
        if (n < N_NODES) s += deg[n];
    }
    red[t] = s;
    __syncthreads();
    for (int o = 128; o > 0; o >>= 1) {
        if (t < o) red[t] += red[t + o];
        __syncthreads();
    }
    if (t == 0) bsum[blockIdx.x] = red[0];
}

__global__ void csr_scan_top_kernel(int* __restrict__ bsum, int* __restrict__ csr_off)
{
    if (threadIdx.x == 0 && blockIdx.x == 0) {
        int run = 0;
        for (int b = 0; b < NB_SCAN; ++b) {
            const int v = bsum[b];
            bsum[b] = run;
            run += v;
        }
        csr_off[N_NODES] = run;   // == N_EDGES
    }
}

__global__ __launch_bounds__(256) void csr_scan_final_kernel(
    const int* __restrict__ bsum, int* __restrict__ cursor,
    int* __restrict__ csr_off)
{
    __shared__ int ts[256];
    const int t = threadIdx.x;
    const int i0 = blockIdx.x * 1024 + t * 4;
    int d[4];
    int s = 0;
#pragma unroll
    for (int j = 0; j < 4; ++j) {
        const int n = i0 + j;
        d[j] = (n < N_NODES) ? cursor[n] : 0;
        s += d[j];
    }
    ts[t] = s;
    __syncthreads();
    for (int o = 1; o < 256; o <<= 1) {
        int v = (t >= o) ? ts[t - o] : 0;
        __syncthreads();
        ts[t] += v;
        __syncthreads();
    }
    int run = bsum[blockIdx.x] + ts[t] - s;
#pragma unroll
    for (int j = 0; j < 4; ++j) {
        const int n = i0 + j;
        if (n < N_NODES) {
            csr_off[n] = run;
            cursor[n] = run;
            run += d[j];
        }
    }
}

__global__ __launch_bounds__(256) void csr_fill_kernel(
    const int* __restrict__ ei, int* __restrict__ cursor,
    int* __restrict__ csr_eid, int* __restrict__ csr_src)
{
    const int e = blockIdx.x * 256 + threadIdx.x;
    if (e >= N_EDGES) return;
    const int dst = ei[N_EDGES + e];
    const int pos = atomicAdd(&cursor[dst], 1);
    csr_eid[pos] = e;
    csr_src[pos] = ei[e];
}

// ---------------------------------------------------------------------------
// Fused attention gather: unchanged from previous round.
// ---------------------------------------------------------------------------
__global__ __launch_bounds__(256) void fused_attn_kernel(
    const int* __restrict__ csr_off, const int* __restrict__ csr_eid,
    const int* __restrict__ csr_src, const unsigned short* __restrict__ Ee,
    const float* __restrict__ Qn, const float* __restrict__ Kn,
    const float* __restrict__ Vn, float* __restrict__ out)
{
    const int lane = threadIdx.x & 63;
    const int l2 = lane * 2;
    const long n = (long)blockIdx.x * 4 + (threadIdx.x >> 6);

    const int off0 = csr_off[n];
    const int off1 = csr_off[n + 1];
    const float2 q = *(const float2*)&Qn[n * 128 + l2];
    float2 acc = *(const float2*)&out[n * 128 + l2];

    float dsum = 0.f;
    for (int base = off0; base < off1; base += 64) {
        const int cnt = min(64, off1 - base);
        int eid = 0, src = 0;
        if (base + lane < off1) {
            eid = csr_eid[base + lane];
            src = csr_src[base + lane];
        }
        for (int j = 0; j < cnt; ++j) {
            const long e = __shfl(eid, j, 64);
            const long s = __shfl(src, j, 64);
            const unsigned u = *(const unsigned*)&Ee[e * 128 + l2];
            const float2 k = *(const float2*)&Kn[s * 128 + l2];
            float p = q.x * (k.x + __uint_as_float(u << 16)) +
                      q.y * (k.y + __uint_as_float(u & 0xffff0000u));
#pragma unroll
            for (int o = 1; o < 16; o <<= 1) p += __shfl_xor(p, o, 64);
            dsum += __expf(p * INV_SQRT32 - M0);
        }
    }
    const float rd = 1.f / (dsum + 1e-16f);

    for (int base = off0; base < off1; base += 64) {
        const int cnt = min(64, off1 - base);
        int eid = 0, src = 0;
        if (base + lane < off1) {
            eid = csr_eid[base + lane];
            src = csr_src[base + lane];
        }
        for (int j = 0; j < cnt; ++j) {
            const long e = __shfl(eid, j, 64);
            const long s = __shfl(src, j, 64);
            const unsigned u = *(const unsigned*)&Ee[e * 128 + l2];
            const float2 k = *(const float2*)&Kn[s * 128 + l2];
            const float ea0 = __uint_as_float(u << 16);
            const float ea1 = __uint_as_float(u & 0xffff0000u);
            float p = q.x * (k.x + ea0) + q.y * (k.y + ea1);
#pragma unroll
            for (int o = 1; o < 16; o <<= 1) p += __shfl_xor(p, o, 64);
            const float an = __expf(p * INV_SQRT32 - M0) * rd;
            const float2 v = *(const float2*)&Vn[s * 128 + l2];
            acc.x = fmaf(v.x + ea0, an, acc.x);
            acc.y = fmaf(v.y + ea1, an, acc.y);
        }
    }
    *(float2*)&out[n * 128 + l2] = acc;
}

// ---------------------------------------------------------------------------
// Workspace layout (float offsets unless noted):
//   Qn      [N,128]   @ 0
//   Kn      [N,128]   @ 12,800,000
//   Vn      [N,128]   @ 25,600,000
//   csr_off [N+1]     @ 38,400,000  (int)
//   cursor  [N]       @ 38,500,004  (int)
//   csr_eid [E]       @ 38,600,004  (int)
//   csr_src [E]       @ 39,100,004  (int)
//   bsum    [98]      @ 39,600,004  (int)
//   WBh     [65536]us @ 40,000,000
//   WBl     [65536]us @ 40,050,000
//   WEh     [8192]us  @ 40,100,000
//   WEl     [8192]us  @ 40,110,000
//   Ee bf16 [E,128]   @ byte 163,200,032
// ---------------------------------------------------------------------------
extern "C" void kernel_launch(void* const* d_in, const int* in_sizes, int n_in,
                              void* d_out, int out_size, void* d_ws, size_t ws_size,
                              hipStream_t stream)
{
    const float* x  = (const float*)d_in[0];
    const int*   ei = (const int*)d_in[1];
    const float* ea = (const float*)d_in[2];
    const float* Wq = (const float*)d_in[3];
    const float* bq = (const float*)d_in[4];
    const float* Wk = (const float*)d_in[5];
    const float* bk = (const float*)d_in[6];
    const float* Wv = (const float*)d_in[7];
    const float* bv = (const float*)d_in[8];
    const float* We = (const float*)d_in[9];
    const float* Ws = (const float*)d_in[10];
    const float* bs = (const float*)d_in[11];
    float* out = (float*)d_out;

    float* ws = (float*)d_ws;
    float* Qn = ws;
    float* Kn = ws + 12800000;
    float* Vn = ws + 25600000;
    int* csr_off = (int*)(ws + 38400000);
    int* cursor  = (int*)(ws + 38500004);
    int* csr_eid = (int*)(ws + 38600004);
    int* csr_src = (int*)(ws + 39100004);
    int* bsum    = (int*)(ws + 39600004);
    unsigned short* WBh = (unsigned short*)(ws + 40000000);
    unsigned short* WBl = (unsigned short*)(ws + 40050000);
    unsigned short* WEh = (unsigned short*)(ws + 40100000);
    unsigned short* WEl = (unsigned short*)(ws + 40110000);
    unsigned short* Ee = (unsigned short*)((char*)d_ws + 163200032);

    hipMemsetAsync(cursor, 0, N_NODES * sizeof(int), stream);

    prep_w_kernel<<<288, 256, 0, stream>>>(Wq, Wk, Wv, Ws, We, WBh, WBl, WEh, WEl);

    node_proj_mfma<<<1563, 256, 0, stream>>>(x, WBh, WBl, bq, bk, bv, bs,
                                             Qn, Kn, Vn, out);
    ee_gemm_mfma<<<3907, 256, 0, stream>>>(ea, WEh, WEl, Ee);

    csr_hist_kernel<<<(N_EDGES + 255) / 256, 256, 0, stream>>>(ei, cursor);
    csr_scan_part_kernel<<<NB_SCAN, 256, 0, stream>>>(cursor, bsum);
    csr_scan_top_kernel<<<1, 64, 0, stream>>>(bsum, csr_off);
    csr_scan_final_kernel<<<NB_SCAN, 256, 0, stream>>>(bsum, cursor, csr_off);
    csr_fill_kernel<<<(N_EDGES + 255) / 256, 256, 0, stream>>>(ei, cursor, csr_eid, csr_src);

    fused_attn_kernel<<<25000, 256, 0, stream>>>(csr_off, csr_eid, csr_src, Ee,
                                                 Qn, Kn, Vn, out);
}

// Round 2
// 599.587 us; speedup vs baseline: 1.1275x; 1.0747x over previous
//
#include <hip/hip_runtime.h>
#include <hip/hip_bf16.h>
#include <math.h>

#define N_NODES 100000
#define N_EDGES 500000
#define M0 8.0f
#define INV_SQRT32 0.17677669529663687f

#define NB_HIST 1954   // ceil(500000/256)
#define NB_PROJ 1563   // ceil(100000/64)
#define NB_EE   3907   // ceil(500000/128)
#define GRID_MEGA (NB_HIST + NB_PROJ + NB_EE)

typedef __attribute__((ext_vector_type(8))) short bf16x8;
typedef __attribute__((ext_vector_type(4))) float f32x4;
typedef __attribute__((ext_vector_type(8))) unsigned short us8;

static __device__ __forceinline__ unsigned short f2bf(float f) {
    __hip_bfloat16 h = __float2bfloat16(f);
    return *(unsigned short*)&h;
}

static __device__ __forceinline__ void split4(float4 v, ushort4& hv, ushort4& lv) {
    const unsigned short h0 = f2bf(v.x), h1 = f2bf(v.y),
                         h2 = f2bf(v.z), h3 = f2bf(v.w);
    hv.x = h0; hv.y = h1; hv.z = h2; hv.w = h3;
    lv.x = f2bf(v.x - __uint_as_float((unsigned)h0 << 16));
    lv.y = f2bf(v.y - __uint_as_float((unsigned)h1 << 16));
    lv.z = f2bf(v.z - __uint_as_float((unsigned)h2 << 16));
    lv.w = f2bf(v.w - __uint_as_float((unsigned)h3 << 16));
}

// ---------------------------------------------------------------------------
// prep: split weights into bf16 hi/lo (Markidis) AND zero the cursor array.
// Replaces prep_w + hipMemsetAsync. One-shot, tiny.
// ---------------------------------------------------------------------------
__global__ __launch_bounds__(256) void prep_kernel(
    const float* __restrict__ Wq, const float* __restrict__ Wk,
    const float* __restrict__ Wv, const float* __restrict__ Ws,
    const float* __restrict__ We,
    unsigned short* __restrict__ WBh, unsigned short* __restrict__ WBl,
    unsigned short* __restrict__ WEh, unsigned short* __restrict__ WEl,
    int* __restrict__ cursor)
{
    const int i = blockIdx.x * 256 + threadIdx.x;
    if (i < N_NODES) cursor[i] = 0;
    if (i < 65536) {
        const int p = i >> 14;
        const float* W = (p == 0) ? Wq : (p == 1) ? Wk : (p == 2) ? Wv : Ws;
        const float v = W[i & 16383];
        const unsigned short h = f2bf(v);
        WBh[i] = h;
        WBl[i] = f2bf(v - __uint_as_float((unsigned)h << 16));
    } else if (i < 73728) {
        const int idx = i - 65536;
        const float v = We[idx];
        const unsigned short h = f2bf(v);
        WEh[idx] = h;
        WEl[idx] = f2bf(v - __uint_as_float((unsigned)h << 16));
    }
}

// ---------------------------------------------------------------------------
// mega: one grid = CSR histogram blocks + node-projection MFMA blocks +
// edge-embedding MFMA blocks. All three are mutually independent; fusing
// removes 2 dispatch boundaries and lets the cheap hist blocks fill the
// GEMM ramp. MFMA math identical to the (verified) Round-1 kernels.
// ---------------------------------------------------------------------------
__global__ __launch_bounds__(256) void mega_kernel(
    const float* __restrict__ x, const int* __restrict__ ei,
    const float* __restrict__ ea,
    const unsigned short* __restrict__ WBh, const unsigned short* __restrict__ WBl,
    const unsigned short* __restrict__ WEh, const unsigned short* __restrict__ WEl,
    const float* __restrict__ bq, const float* __restrict__ bk,
    const float* __restrict__ bv, const float* __restrict__ bs,
    float* __restrict__ Qn, float* __restrict__ Kn, float* __restrict__ Vn,
    float* __restrict__ out, unsigned short* __restrict__ Ee,
    int* __restrict__ cursor)
{
    __shared__ __align__(16) unsigned short sAh[8192];
    __shared__ __align__(16) unsigned short sAl[8192];
    __shared__ __align__(16) unsigned short sWh[8192];
    __shared__ __align__(16) unsigned short sWl[8192];

    const int t = threadIdx.x;
    const int bid = blockIdx.x;

    // ---- CSR histogram blocks ----
    if (bid < NB_HIST) {
        const int e = bid * 256 + t;
        if (e < N_EDGES) atomicAdd(&cursor[ei[N_EDGES + e]], 1);
        return;
    }

    const int lane = t & 63;
    const int fr = lane & 15;
    const int fq = lane >> 4;

    if (bid < NB_HIST + NB_PROJ) {
        // ---- node projection: 64 rows x (Q,K,V,S) ----
        const long r0 = (long)(bid - NB_HIST) * 64;
        const int wid = t >> 6;      // wave owns cols wid*32..wid*32+31

        // stage x tile [64][128] -> hi/lo bf16, swizzled
        for (int i = t; i < 2048; i += 256) {
            const int r = i >> 5;
            const int k4 = (i & 31) * 4;
            const long row = r0 + r;
            float4 v = (row < N_NODES) ? *(const float4*)&x[row * 128 + k4]
                                       : make_float4(0.f, 0.f, 0.f, 0.f);
            ushort4 hv, lv; split4(v, hv, lv);
            const int di = r * 128 + (k4 ^ ((r & 7) << 3));
            *(ushort4*)&sAh[di] = hv;
            *(ushort4*)&sAl[di] = lv;
        }

        for (int p = 0; p < 4; ++p) {
            const float* bias = (p == 0) ? bq : (p == 1) ? bk : (p == 2) ? bv : bs;
            float* dst        = (p == 0) ? Qn : (p == 1) ? Kn : (p == 2) ? Vn : out;

            f32x4 acc[4][2];
#pragma unroll
            for (int m = 0; m < 4; ++m)
#pragma unroll
                for (int n = 0; n < 2; ++n) acc[m][n] = (f32x4){0.f, 0.f, 0.f, 0.f};

            for (int kc = 0; kc < 2; ++kc) {
                __syncthreads();
                // stage pre-split W chunk [128 ch][64 k]
                for (int i = t; i < 1024; i += 256) {
                    const int r = i >> 3;
                    const int s = i & 7;
                    const int gi = p * 16384 + r * 128 + kc * 64 + s * 8;
                    const int di = r * 64 + ((s * 8) ^ ((r & 7) << 3));
                    *(us8*)&sWh[di] = *(const us8*)&WBh[gi];
                    *(us8*)&sWl[di] = *(const us8*)&WBl[gi];
                }
                __syncthreads();

#pragma unroll
                for (int ks = 0; ks < 2; ++ks) {
                    const int kx = kc * 64 + ks * 32 + fq * 8;
                    const int kw = ks * 32 + fq * 8;
                    bf16x8 ah[4], al[4], bh[2], bl[2];
#pragma unroll
                    for (int m = 0; m < 4; ++m) {
                        const int r = m * 16 + fr;
                        const int di = r * 128 + (kx ^ ((r & 7) << 3));
                        ah[m] = *(const bf16x8*)&sAh[di];
                        al[m] = *(const bf16x8*)&sAl[di];
                    }
#pragma unroll
                    for (int n = 0; n < 2; ++n) {
                        const int r = wid * 32 + n * 16 + fr;
                        const int di = r * 64 + (kw ^ ((r & 7) << 3));
                        bh[n] = *(const bf16x8*)&sWh[di];
                        bl[n] = *(const bf16x8*)&sWl[di];
                    }
#pragma unroll
                    for (int m = 0; m < 4; ++m)
#pragma unroll
                        for (int n = 0; n < 2; ++n) {
                            acc[m][n] = __builtin_amdgcn_mfma_f32_16x16x32_bf16(
                                ah[m], bh[n], acc[m][n], 0, 0, 0);
                            acc[m][n] = __builtin_amdgcn_mfma_f32_16x16x32_bf16(
                                ah[m], bl[n], acc[m][n], 0, 0, 0);
                            acc[m][n] = __builtin_amdgcn_mfma_f32_16x16x32_bf16(
                                al[m], bh[n], acc[m][n], 0, 0, 0);
                        }
                }
            }

            float bb[2];
#pragma unroll
            for (int n = 0; n < 2; ++n) bb[n] = bias[wid * 32 + n * 16 + fr];
#pragma unroll
            for (int m = 0; m < 4; ++m) {
                const long rowb = r0 + m * 16 + fq * 4;
#pragma unroll
                for (int j = 0; j < 4; ++j) {
                    if (rowb + j < N_NODES) {
#pragma unroll
                        for (int n = 0; n < 2; ++n)
                            dst[(rowb + j) * 128 + wid * 32 + n * 16 + fr] =
                                acc[m][n][j] + bb[n];
                    }
                }
            }
        }
    } else {
        // ---- edge embedding GEMM: Ee = ea @ We^T, bf16 out ----
        const long e0 = (long)(bid - NB_HIST - NB_PROJ) * 128;
        const int wr = (t >> 6) >> 1;
        const int wc = (t >> 6) & 1;

        for (int i = t; i < 1024; i += 256) {
            const int r = i >> 3;
            const int s = i & 7;
            const int di = r * 64 + ((s * 8) ^ ((r & 7) << 3));
            *(us8*)&sWh[di] = *(const us8*)&WEh[r * 64 + s * 8];
            *(us8*)&sWl[di] = *(const us8*)&WEl[r * 64 + s * 8];
        }
        for (int i = t; i < 2048; i += 256) {
            const int r = i >> 4;
            const int k4 = (i & 15) * 4;
            const long e = e0 + r;
            float4 v = (e < N_EDGES) ? *(const float4*)&ea[e * 64 + k4]
                                     : make_float4(0.f, 0.f, 0.f, 0.f);
            ushort4 hv, lv; split4(v, hv, lv);
            const int di = r * 64 + (k4 ^ ((r & 7) << 3));
            *(ushort4*)&sAh[di] = hv;
            *(ushort4*)&sAl[di] = lv;
        }
        __syncthreads();

        f32x4 acc[4][4];
#pragma unroll
        for (int m = 0; m < 4; ++m)
#pragma unroll
            for (int n = 0; n < 4; ++n) acc[m][n] = (f32x4){0.f, 0.f, 0.f, 0.f};

#pragma unroll
        for (int ks = 0; ks < 2; ++ks) {
            const int kk = ks * 32 + fq * 8;
            bf16x8 ah[4], al[4], bh[4], bl[4];
#pragma unroll
            for (int m = 0; m < 4; ++m) {
                const int r = wr * 64 + m * 16 + fr;
                const int di = r * 64 + (kk ^ ((r & 7) << 3));
                ah[m] = *(const bf16x8*)&sAh[di];
                al[m] = *(const bf16x8*)&sAl[di];
            }
#pragma unroll
            for (int n = 0; n < 4; ++n) {
                const int r = wc * 64 + n * 16 + fr;
                const int di = r * 64 + (kk ^ ((r & 7) << 3));
                bh[n] = *(const bf16x8*)&sWh[di];
                bl[n] = *(const bf16x8*)&sWl[di];
            }
#pragma unroll
            for (int m = 0; m < 4; ++m)
#pragma unroll
                for (int n = 0; n < 4; ++n) {
                    acc[m][n] = __builtin_amdgcn_mfma_f32_16x16x32_bf16(
                        ah[m], bh[n], acc[m][n], 0, 0, 0);
                    acc[m][n] = __builtin_amdgcn_mfma_f32_16x16x32_bf16(
                        ah[m], bl[n], acc[m][n], 0, 0, 0);
                    acc[m][n] = __builtin_amdgcn_mfma_f32_16x16x32_bf16(
                        al[m], bh[n], acc[m][n], 0, 0, 0);
                }
        }

#pragma unroll
        for (int m = 0; m < 4; ++m) {
            const long erow = e0 + wr * 64 + m * 16 + fq * 4;
#pragma unroll
            for (int j = 0; j < 4; ++j) {
                if (erow + j < N_EDGES) {
#pragma unroll
                    for (int n = 0; n < 4; ++n)
                        Ee[(erow + j) * 128 + wc * 64 + n * 16 + fr] =
                            f2bf(acc[m][n][j]);
                }
            }
        }
    }
}

// ---------------------------------------------------------------------------
// CSR scan: single block, 1024 threads. Thread t owns nodes [t*100, t*100+100).
// Replaces the 3-kernel scan chain (part/top/final) + bsum buffer.
// ---------------------------------------------------------------------------
__global__ __launch_bounds__(1024) void csr_scan_kernel(
    int* __restrict__ cursor, int* __restrict__ csr_off)
{
    __shared__ int wsum[16];
    const int t = threadIdx.x;
    const int lane = t & 63;
    const int wid = t >> 6;
    const int n0 = t * 100;
    const bool active = (t < 1000);

    int tsum = 0;
    if (active) {
        for (int q = 0; q < 25; ++q) {
            const int4 d = *(const int4*)&cursor[n0 + q * 4];
            tsum += d.x + d.y + d.z + d.w;
        }
    }
    int inc = tsum;
#pragma unroll
    for (int o = 1; o < 64; o <<= 1) {
        const int v = __shfl_up(inc, o, 64);
        if (lane >= o) inc += v;
    }
    if (lane == 63) wsum[wid] = inc;
    __syncthreads();
    if (t == 0) {
        int run = 0;
#pragma unroll
        for (int w = 0; w < 16; ++w) { const int v = wsum[w]; wsum[w] = run; run += v; }
        csr_off[N_NODES] = run;   // == N_EDGES
    }
    __syncthreads();
    if (active) {
        int run = wsum[wid] + inc - tsum;   // exclusive prefix for first node
        for (int q = 0; q < 25; ++q) {
            const int n = n0 + q * 4;
            const int4 d = *(const int4*)&cursor[n];
            int4 offv;
            offv.x = run; run += d.x;
            offv.y = run; run += d.y;
            offv.z = run; run += d.z;
            offv.w = run; run += d.w;
            *(int4*)&csr_off[n] = offv;
            *(int4*)&cursor[n]  = offv;
        }
    }
}

__global__ __launch_bounds__(256) void csr_fill_kernel(
    const int* __restrict__ ei, int* __restrict__ cursor,
    int* __restrict__ csr_eid, int* __restrict__ csr_src)
{
    const int e = blockIdx.x * 256 + threadIdx.x;
    if (e >= N_EDGES) return;
    const int dst = ei[N_EDGES + e];
    const int pos = atomicAdd(&cursor[dst], 1);
    csr_eid[pos] = e;
    csr_src[pos] = ei[e];
}

// ---------------------------------------------------------------------------
// Fused attention gather — SINGLE PASS. exp(p-M)/Σexp(p-M) is invariant in M,
// so with fixed M0 the numerator and denominator accumulate together:
// acc += exp(p-M0)*(v+e); dsum += exp(p-M0); out += acc/dsum.
// Halves Ee/Kn traffic and the serial per-edge VALU work vs the 2-pass form.
// ---------------------------------------------------------------------------
__global__ __launch_bounds__(256) void fused_attn_kernel(
    const int* __restrict__ csr_off, const int* __restrict__ csr_eid,
    const int* __restrict__ csr_src, const unsigned short* __restrict__ Ee,
    const float* __restrict__ Qn, const float* __restrict__ Kn,
    const float* __restrict__ Vn, float* __restrict__ out)
{
    const int lane = threadIdx.x & 63;
    const int l2 = lane * 2;
    const long n = (long)blockIdx.x * 4 + (threadIdx.x >> 6);

    const int off0 = csr_off[n];
    const int off1 = csr_off[n + 1];
    const float2 q = *(const float2*)&Qn[n * 128 + l2];

    float dsum = 0.f;
    float2 acc = make_float2(0.f, 0.f);
    for (int base = off0; base < off1; base += 64) {
        const int cnt = min(64, off1 - base);
        int eid = 0, src = 0;
        if (base + lane < off1) {
            eid = csr_eid[base + lane];
            src = csr_src[base + lane];
        }
        for (int j = 0; j < cnt; ++j) {
            const long e = __shfl(eid, j, 64);
            const long s = __shfl(src, j, 64);
            const unsigned u = *(const unsigned*)&Ee[e * 128 + l2];
            const float2 k = *(const float2*)&Kn[s * 128 + l2];
            const float ea0 = __uint_as_float(u << 16);
            const float ea1 = __uint_as_float(u & 0xffff0000u);
            float p = q.x * (k.x + ea0) + q.y * (k.y + ea1);
#pragma unroll
            for (int o = 1; o < 16; o <<= 1) p += __shfl_xor(p, o, 64);
            const float an = __expf(p * INV_SQRT32 - M0);
            dsum += an;
            const float2 v = *(const float2*)&Vn[s * 128 + l2];
            acc.x = fmaf(v.x + ea0, an, acc.x);
            acc.y = fmaf(v.y + ea1, an, acc.y);
        }
    }
    const float rd = 1.f / (dsum + 1e-16f);
    float2 o = *(const float2*)&out[n * 128 + l2];
    o.x = fmaf(acc.x, rd, o.x);
    o.y = fmaf(acc.y, rd, o.y);
    *(float2*)&out[n * 128 + l2] = o;
}

// ---------------------------------------------------------------------------
// Workspace layout (float offsets unless noted):
//   Qn      [N,128]   @ 0
//   Kn      [N,128]   @ 12,800,000
//   Vn      [N,128]   @ 25,600,000
//   csr_off [N+1]     @ 38,400,000  (int)
//   cursor  [N]       @ 38,500,004  (int)
//   csr_eid [E]       @ 38,600,004  (int)
//   csr_src [E]       @ 39,100,004  (int)
//   WBh     [65536]us @ 40,000,000
//   WBl     [65536]us @ 40,050,000
//   WEh     [8192]us  @ 40,100,000
//   WEl     [8192]us  @ 40,110,000
//   Ee bf16 [E,128]   @ byte 163,200,032
// ---------------------------------------------------------------------------
extern "C" void kernel_launch(void* const* d_in, const int* in_sizes, int n_in,
                              void* d_out, int out_size, void* d_ws, size_t ws_size,
                              hipStream_t stream)
{
    const float* x  = (const float*)d_in[0];
    const int*   ei = (const int*)d_in[1];
    const float* ea = (const float*)d_in[2];
    const float* Wq = (const float*)d_in[3];
    const float* bq = (const float*)d_in[4];
    const float* Wk = (const float*)d_in[5];
    const float* bk = (const float*)d_in[6];
    const float* Wv = (const float*)d_in[7];
    const float* bv = (const float*)d_in[8];
    const float* We = (const float*)d_in[9];
    const float* Ws = (const float*)d_in[10];
    const float* bs = (const float*)d_in[11];
    float* out = (float*)d_out;

    float* ws = (float*)d_ws;
    float* Qn = ws;
    float* Kn = ws + 12800000;
    float* Vn = ws + 25600000;
    int* csr_off = (int*)(ws + 38400000);
    int* cursor  = (int*)(ws + 38500004);
    int* csr_eid = (int*)(ws + 38600004);
    int* csr_src = (int*)(ws + 39100004);
    unsigned short* WBh = (unsigned short*)(ws + 40000000);
    unsigned short* WBl = (unsigned short*)(ws + 40050000);
    unsigned short* WEh = (unsigned short*)(ws + 40100000);
    unsigned short* WEl = (unsigned short*)(ws + 40110000);
    unsigned short* Ee = (unsigned short*)((char*)d_ws + 163200032);

    // 5 dispatches total (was 10).
    prep_kernel<<<391, 256, 0, stream>>>(Wq, Wk, Wv, Ws, We,
                                         WBh, WBl, WEh, WEl, cursor);

    mega_kernel<<<GRID_MEGA, 256, 0, stream>>>(x, ei, ea,
                                               WBh, WBl, WEh, WEl,
                                               bq, bk, bv, bs,
                                               Qn, Kn, Vn, out, Ee, cursor);

    csr_scan_kernel<<<1, 1024, 0, stream>>>(cursor, csr_off);

    csr_fill_kernel<<<NB_HIST, 256, 0, stream>>>(ei, cursor, csr_eid, csr_src);

    fused_attn_kernel<<<25000, 256, 0, stream>>>(csr_off, csr_eid, csr_src, Ee,
                                                 Qn, Kn, Vn, out);
}

// Round 3
// 575.852 us; speedup vs baseline: 1.1740x; 1.0412x over previous
//
#include <hip/hip_runtime.h>
#include <hip/hip_bf16.h>
#include <math.h>

#define N_NODES 100000
#define N_EDGES 500000
#define M0 8.0f
#define INV_SQRT32 0.17677669529663687f

#define NB_HIST 977    // ceil(500000/512)
#define NB_PROJ 1563   // ceil(100000/64)
#define NB_EE   3907   // ceil(500000/128)
#define GRID_MEGA (NB_HIST + NB_PROJ + NB_EE)

typedef __attribute__((ext_vector_type(8))) short bf16x8;
typedef __attribute__((ext_vector_type(4))) float f32x4;
typedef __attribute__((ext_vector_type(8))) unsigned short us8;

static __device__ __forceinline__ unsigned short f2bf(float f) {
    __hip_bfloat16 h = __float2bfloat16(f);
    return *(unsigned short*)&h;
}

static __device__ __forceinline__ void split4(float4 v, ushort4& hv, ushort4& lv) {
    const unsigned short h0 = f2bf(v.x), h1 = f2bf(v.y),
                         h2 = f2bf(v.z), h3 = f2bf(v.w);
    hv.x = h0; hv.y = h1; hv.z = h2; hv.w = h3;
    lv.x = f2bf(v.x - __uint_as_float((unsigned)h0 << 16));
    lv.y = f2bf(v.y - __uint_as_float((unsigned)h1 << 16));
    lv.z = f2bf(v.z - __uint_as_float((unsigned)h2 << 16));
    lv.w = f2bf(v.w - __uint_as_float((unsigned)h3 << 16));
}

// ---------------------------------------------------------------------------
// prep: split weights into bf16 hi/lo (Markidis) AND zero the cursor array.
// ---------------------------------------------------------------------------
__global__ __launch_bounds__(256) void prep_kernel(
    const float* __restrict__ Wq, const float* __restrict__ Wk,
    const float* __restrict__ Wv, const float* __restrict__ Ws,
    const float* __restrict__ We,
    unsigned short* __restrict__ WBh, unsigned short* __restrict__ WBl,
    unsigned short* __restrict__ WEh, unsigned short* __restrict__ WEl,
    int* __restrict__ cursor)
{
    const int i = blockIdx.x * 256 + threadIdx.x;
    if (i < N_NODES) cursor[i] = 0;
    if (i < 65536) {
        const int p = i >> 14;
        const float* W = (p == 0) ? Wq : (p == 1) ? Wk : (p == 2) ? Wv : Ws;
        const float v = W[i & 16383];
        const unsigned short h = f2bf(v);
        WBh[i] = h;
        WBl[i] = f2bf(v - __uint_as_float((unsigned)h << 16));
    } else if (i < 73728) {
        const int idx = i - 65536;
        const float v = We[idx];
        const unsigned short h = f2bf(v);
        WEh[idx] = h;
        WEl[idx] = f2bf(v - __uint_as_float((unsigned)h << 16));
    }
}

// ---------------------------------------------------------------------------
// mega: hist + node-proj MFMA + edge-embed MFMA in one grid.
// 512-thread blocks (8 waves) with the same 64KB LDS tiles as Round 2:
// 2 blocks/CU -> 16 waves/CU (was 8). Occupancy was the Round-2 bottleneck
// (hbm_gbps==bytes/dur==2.0 TB/s, all pipes idle).
// ---------------------------------------------------------------------------
__global__ __launch_bounds__(512, 4) void mega_kernel(
    const float* __restrict__ x, const int* __restrict__ ei,
    const float* __restrict__ ea,
    const unsigned short* __restrict__ WBh, const unsigned short* __restrict__ WBl,
    const unsigned short* __restrict__ WEh, const unsigned short* __restrict__ WEl,
    const float* __restrict__ bq, const float* __restrict__ bk,
    const float* __restrict__ bv, const float* __restrict__ bs,
    float* __restrict__ Qn, float* __restrict__ Kn, float* __restrict__ Vn,
    float* __restrict__ out, unsigned short* __restrict__ Ee,
    int* __restrict__ cursor)
{
    __shared__ __align__(16) unsigned short sAh[8192];
    __shared__ __align__(16) unsigned short sAl[8192];
    __shared__ __align__(16) unsigned short sWh[8192];
    __shared__ __align__(16) unsigned short sWl[8192];

    const int t = threadIdx.x;
    const int bid = blockIdx.x;

    // ---- CSR histogram blocks ----
    if (bid < NB_HIST) {
        const int e = bid * 512 + t;
        if (e < N_EDGES) atomicAdd(&cursor[ei[N_EDGES + e]], 1);
        return;
    }

    const int lane = t & 63;
    const int wid = t >> 6;          // 0..7
    const int fr = lane & 15;
    const int fq = lane >> 4;

    if (bid < NB_HIST + NB_PROJ) {
        // ---- node projection: 64 rows x (Q,K,V,S); wave owns 16 cols ----
        const long r0 = (long)(bid - NB_HIST) * 64;

        for (int i = t; i < 2048; i += 512) {
            const int r = i >> 5;
            const int k4 = (i & 31) * 4;
            const long row = r0 + r;
            float4 v = (row < N_NODES) ? *(const float4*)&x[row * 128 + k4]
                                       : make_float4(0.f, 0.f, 0.f, 0.f);
            ushort4 hv, lv; split4(v, hv, lv);
            const int di = r * 128 + (k4 ^ ((r & 7) << 3));
            *(ushort4*)&sAh[di] = hv;
            *(ushort4*)&sAl[di] = lv;
        }

        for (int p = 0; p < 4; ++p) {
            const float* bias = (p == 0) ? bq : (p == 1) ? bk : (p == 2) ? bv : bs;
            float* dst        = (p == 0) ? Qn : (p == 1) ? Kn : (p == 2) ? Vn : out;

            f32x4 acc[4];
#pragma unroll
            for (int m = 0; m < 4; ++m) acc[m] = (f32x4){0.f, 0.f, 0.f, 0.f};

            for (int kc = 0; kc < 2; ++kc) {
                __syncthreads();
                for (int i = t; i < 1024; i += 512) {
                    const int r = i >> 3;
                    const int s = i & 7;
                    const int gi = p * 16384 + r * 128 + kc * 64 + s * 8;
                    const int di = r * 64 + ((s * 8) ^ ((r & 7) << 3));
                    *(us8*)&sWh[di] = *(const us8*)&WBh[gi];
                    *(us8*)&sWl[di] = *(const us8*)&WBl[gi];
                }
                __syncthreads();

#pragma unroll
                for (int ks = 0; ks < 2; ++ks) {
                    const int kx = kc * 64 + ks * 32 + fq * 8;
                    const int kw = ks * 32 + fq * 8;
                    bf16x8 ah[4], al[4], bh, bl;
#pragma unroll
                    for (int m = 0; m < 4; ++m) {
                        const int r = m * 16 + fr;
                        const int di = r * 128 + (kx ^ ((r & 7) << 3));
                        ah[m] = *(const bf16x8*)&sAh[di];
                        al[m] = *(const bf16x8*)&sAl[di];
                    }
                    {
                        const int r = wid * 16 + fr;
                        const int di = r * 64 + (kw ^ ((r & 7) << 3));
                        bh = *(const bf16x8*)&sWh[di];
                        bl = *(const bf16x8*)&sWl[di];
                    }
#pragma unroll
                    for (int m = 0; m < 4; ++m) {
                        acc[m] = __builtin_amdgcn_mfma_f32_16x16x32_bf16(
                            ah[m], bh, acc[m], 0, 0, 0);
                        acc[m] = __builtin_amdgcn_mfma_f32_16x16x32_bf16(
                            ah[m], bl, acc[m], 0, 0, 0);
                        acc[m] = __builtin_amdgcn_mfma_f32_16x16x32_bf16(
                            al[m], bh, acc[m], 0, 0, 0);
                    }
                }
            }

            const float bb = bias[wid * 16 + fr];
#pragma unroll
            for (int m = 0; m < 4; ++m) {
                const long rowb = r0 + m * 16 + fq * 4;
#pragma unroll
                for (int j = 0; j < 4; ++j) {
                    if (rowb + j < N_NODES)
                        dst[(rowb + j) * 128 + wid * 16 + fr] = acc[m][j] + bb;
                }
            }
        }
    } else {
        // ---- edge embedding GEMM: 128x128 tile; 8 waves in 2x4 ----
        const long e0 = (long)(bid - NB_HIST - NB_PROJ) * 128;
        const int wr = wid >> 2;     // 0..1: rows wr*64
        const int wc = wid & 3;      // 0..3: cols wc*32

        for (int i = t; i < 1024; i += 512) {
            const int r = i >> 3;
            const int s = i & 7;
            const int di = r * 64 + ((s * 8) ^ ((r & 7) << 3));
            *(us8*)&sWh[di] = *(const us8*)&WEh[r * 64 + s * 8];
            *(us8*)&sWl[di] = *(const us8*)&WEl[r * 64 + s * 8];
        }
        for (int i = t; i < 2048; i += 512) {
            const int r = i >> 4;
            const int k4 = (i & 15) * 4;
            const long e = e0 + r;
            float4 v = (e < N_EDGES) ? *(const float4*)&ea[e * 64 + k4]
                                     : make_float4(0.f, 0.f, 0.f, 0.f);
            ushort4 hv, lv; split4(v, hv, lv);
            const int di = r * 64 + (k4 ^ ((r & 7) << 3));
            *(ushort4*)&sAh[di] = hv;
            *(ushort4*)&sAl[di] = lv;
        }
        __syncthreads();

        f32x4 acc[4][2];
#pragma unroll
        for (int m = 0; m < 4; ++m)
#pragma unroll
            for (int n = 0; n < 2; ++n) acc[m][n] = (f32x4){0.f, 0.f, 0.f, 0.f};

#pragma unroll
        for (int ks = 0; ks < 2; ++ks) {
            const int kk = ks * 32 + fq * 8;
            bf16x8 ah[4], al[4], bh[2], bl[2];
#pragma unroll
            for (int m = 0; m < 4; ++m) {
                const int r = wr * 64 + m * 16 + fr;
                const int di = r * 64 + (kk ^ ((r & 7) << 3));
                ah[m] = *(const bf16x8*)&sAh[di];
                al[m] = *(const bf16x8*)&sAl[di];
            }
#pragma unroll
            for (int n = 0; n < 2; ++n) {
                const int r = wc * 32 + n * 16 + fr;
                const int di = r * 64 + (kk ^ ((r & 7) << 3));
                bh[n] = *(const bf16x8*)&sWh[di];
                bl[n] = *(const bf16x8*)&sWl[di];
            }
#pragma unroll
            for (int m = 0; m < 4; ++m)
#pragma unroll
                for (int n = 0; n < 2; ++n) {
                    acc[m][n] = __builtin_amdgcn_mfma_f32_16x16x32_bf16(
                        ah[m], bh[n], acc[m][n], 0, 0, 0);
                    acc[m][n] = __builtin_amdgcn_mfma_f32_16x16x32_bf16(
                        ah[m], bl[n], acc[m][n], 0, 0, 0);
                    acc[m][n] = __builtin_amdgcn_mfma_f32_16x16x32_bf16(
                        al[m], bh[n], acc[m][n], 0, 0, 0);
                }
        }

#pragma unroll
        for (int m = 0; m < 4; ++m) {
            const long erow = e0 + wr * 64 + m * 16 + fq * 4;
#pragma unroll
            for (int j = 0; j < 4; ++j) {
                if (erow + j < N_EDGES) {
#pragma unroll
                    for (int n = 0; n < 2; ++n)
                        Ee[(erow + j) * 128 + wc * 32 + n * 16 + fr] =
                            f2bf(acc[m][n][j]);
                }
            }
        }
    }
}

// ---------------------------------------------------------------------------
// CSR scan: single block, 1024 threads.
// ---------------------------------------------------------------------------
__global__ __launch_bounds__(1024) void csr_scan_kernel(
    int* __restrict__ cursor, int* __restrict__ csr_off)
{
    __shared__ int wsum[16];
    const int t = threadIdx.x;
    const int lane = t & 63;
    const int wid = t >> 6;
    const int n0 = t * 100;
    const bool active = (t < 1000);

    int tsum = 0;
    if (active) {
        for (int q = 0; q < 25; ++q) {
            const int4 d = *(const int4*)&cursor[n0 + q * 4];
            tsum += d.x + d.y + d.z + d.w;
        }
    }
    int inc = tsum;
#pragma unroll
    for (int o = 1; o < 64; o <<= 1) {
        const int v = __shfl_up(inc, o, 64);
        if (lane >= o) inc += v;
    }
    if (lane == 63) wsum[wid] = inc;
    __syncthreads();
    if (t == 0) {
        int run = 0;
#pragma unroll
        for (int w = 0; w < 16; ++w) { const int v = wsum[w]; wsum[w] = run; run += v; }
        csr_off[N_NODES] = run;
    }
    __syncthreads();
    if (active) {
        int run = wsum[wid] + inc - tsum;
        for (int q = 0; q < 25; ++q) {
            const int n = n0 + q * 4;
            const int4 d = *(const int4*)&cursor[n];
            int4 offv;
            offv.x = run; run += d.x;
            offv.y = run; run += d.y;
            offv.z = run; run += d.z;
            offv.w = run; run += d.w;
            *(int4*)&csr_off[n] = offv;
            *(int4*)&cursor[n]  = offv;
        }
    }
}

__global__ __launch_bounds__(256) void csr_fill_kernel(
    const int* __restrict__ ei, int* __restrict__ cursor,
    int* __restrict__ csr_eid, int* __restrict__ csr_src)
{
    const int e = blockIdx.x * 256 + threadIdx.x;
    if (e >= N_EDGES) return;
    const int dst = ei[N_EDGES + e];
    const int pos = atomicAdd(&cursor[dst], 1);
    csr_eid[pos] = e;
    csr_src[pos] = ei[e];
}

// ---------------------------------------------------------------------------
// Fused attention, single pass, 4 edges in flight per wave.
// 16-lane group g owns one edge and ALL 128 channels: lane i holds
// channels {h*32+2i, h*32+2i+1} for h=0..3. Per-head dot reduces with
// shfl_xor o=1..8 (in-group). dsum/acc reduced across groups once at the
// end; group g writes head g. 4x edge-level ILP vs Round 2.
// ---------------------------------------------------------------------------
__global__ __launch_bounds__(256) void fused_attn_kernel(
    const int* __restrict__ csr_off, const int* __restrict__ csr_eid,
    const int* __restrict__ csr_src, const unsigned short* __restrict__ Ee,
    const float* __restrict__ Qn, const float* __restrict__ Kn,
    const float* __restrict__ Vn, float* __restrict__ out)
{
    const int lane = threadIdx.x & 63;
    const int g = lane >> 4;         // group 0..3 (one edge each)
    const int i2 = (lane & 15) * 2;  // channel pair within head
    const long n = (long)blockIdx.x * 4 + (threadIdx.x >> 6);

    const int off0 = csr_off[n];
    const int off1 = csr_off[n + 1];

    float2 q[4];
#pragma unroll
    for (int h = 0; h < 4; ++h)
        q[h] = *(const float2*)&Qn[n * 128 + h * 32 + i2];

    float dsum[4] = {0.f, 0.f, 0.f, 0.f};
    float2 acc[4];
#pragma unroll
    for (int h = 0; h < 4; ++h) acc[h] = make_float2(0.f, 0.f);

    for (int base = off0; base < off1; base += 64) {
        const int cnt = min(64, off1 - base);
        int eid = 0, src = 0;
        if (base + lane < off1) {
            eid = csr_eid[base + lane];
            src = csr_src[base + lane];
        }
        for (int c0 = 0; c0 < cnt; c0 += 4) {
            const int j = c0 + g;              // <= 63 always
            const bool valid = (j < cnt);
            const long e = __shfl(eid, j, 64);
            const long s = __shfl(src, j, 64);

            float ph[4];
            float ea0[4], ea1[4];
            float2 vv[4];
            if (valid) {
#pragma unroll
                for (int h = 0; h < 4; ++h) {
                    const int ch = h * 32 + i2;
                    const unsigned u = *(const unsigned*)&Ee[e * 128 + ch];
                    ea0[h] = __uint_as_float(u << 16);
                    ea1[h] = __uint_as_float(u & 0xffff0000u);
                    const float2 k = *(const float2*)&Kn[s * 128 + ch];
                    vv[h] = *(const float2*)&Vn[s * 128 + ch];
                    ph[h] = q[h].x * (k.x + ea0[h]) + q[h].y * (k.y + ea1[h]);
                }
            } else {
#pragma unroll
                for (int h = 0; h < 4; ++h) ph[h] = 0.f;
            }
#pragma unroll
            for (int h = 0; h < 4; ++h) {
#pragma unroll
                for (int o = 1; o < 16; o <<= 1)
                    ph[h] += __shfl_xor(ph[h], o, 64);
            }
            if (valid) {
#pragma unroll
                for (int h = 0; h < 4; ++h) {
                    const float an = __expf(ph[h] * INV_SQRT32 - M0);
                    dsum[h] += an;
                    acc[h].x = fmaf(vv[h].x + ea0[h], an, acc[h].x);
                    acc[h].y = fmaf(vv[h].y + ea1[h], an, acc[h].y);
                }
            }
        }
    }

    // cross-group reduction (lanes l, l^16, l^32, l^48 hold same channels)
#pragma unroll
    for (int h = 0; h < 4; ++h) {
#pragma unroll
        for (int o = 16; o < 64; o <<= 1) {
            dsum[h] += __shfl_xor(dsum[h], o, 64);
            acc[h].x += __shfl_xor(acc[h].x, o, 64);
            acc[h].y += __shfl_xor(acc[h].y, o, 64);
        }
    }

    const float rd = 1.f / (dsum[g] + 1e-16f);
    float2 o = *(const float2*)&out[n * 128 + g * 32 + i2];
    o.x = fmaf(acc[g].x, rd, o.x);
    o.y = fmaf(acc[g].y, rd, o.y);
    *(float2*)&out[n * 128 + g * 32 + i2] = o;
}

// ---------------------------------------------------------------------------
// Workspace layout (float offsets unless noted):
//   Qn      [N,128]   @ 0
//   Kn      [N,128]   @ 12,800,000
//   Vn      [N,128]   @ 25,600,000
//   csr_off [N+1]     @ 38,400,000  (int)
//   cursor  [N]       @ 38,500,004  (int)
//   csr_eid [E]       @ 38,600,004  (int)
//   csr_src [E]       @ 39,100,004  (int)
//   WBh     [65536]us @ 40,000,000
//   WBl     [65536]us @ 40,050,000
//   WEh     [8192]us  @ 40,100,000
//   WEl     [8192]us  @ 40,110,000
//   Ee bf16 [E,128]   @ byte 163,200,032
// ---------------------------------------------------------------------------
extern "C" void kernel_launch(void* const* d_in, const int* in_sizes, int n_in,
                              void* d_out, int out_size, void* d_ws, size_t ws_size,
                              hipStream_t stream)
{
    const float* x  = (const float*)d_in[0];
    const int*   ei = (const int*)d_in[1];
    const float* ea = (const float*)d_in[2];
    const float* Wq = (const float*)d_in[3];
    const float* bq = (const float*)d_in[4];
    const float* Wk = (const float*)d_in[5];
    const float* bk = (const float*)d_in[6];
    const float* Wv = (const float*)d_in[7];
    const float* bv = (const float*)d_in[8];
    const float* We = (const float*)d_in[9];
    const float* Ws = (const float*)d_in[10];
    const float* bs = (const float*)d_in[11];
    float* out = (float*)d_out;

    float* ws = (float*)d_ws;
    float* Qn = ws;
    float* Kn = ws + 12800000;
    float* Vn = ws + 25600000;
    int* csr_off = (int*)(ws + 38400000);
    int* cursor  = (int*)(ws + 38500004);
    int* csr_eid = (int*)(ws + 38600004);
    int* csr_src = (int*)(ws + 39100004);
    unsigned short* WBh = (unsigned short*)(ws + 40000000);
    unsigned short* WBl = (unsigned short*)(ws + 40050000);
    unsigned short* WEh = (unsigned short*)(ws + 40100000);
    unsigned short* WEl = (unsigned short*)(ws + 40110000);
    unsigned short* Ee = (unsigned short*)((char*)d_ws + 163200032);

    prep_kernel<<<391, 256, 0, stream>>>(Wq, Wk, Wv, Ws, We,
                                         WBh, WBl, WEh, WEl, cursor);

    mega_kernel<<<GRID_MEGA, 512, 0, stream>>>(x, ei, ea,
                                               WBh, WBl, WEh, WEl,
                                               bq, bk, bv, bs,
                                               Qn, Kn, Vn, out, Ee, cursor);

    csr_scan_kernel<<<1, 1024, 0, stream>>>(cursor, csr_off);

    csr_fill_kernel<<<(N_EDGES + 255) / 256, 256, 0, stream>>>(ei, cursor,
                                                               csr_eid, csr_src);

    fused_attn_kernel<<<25000, 256, 0, stream>>>(csr_off, csr_eid, csr_src, Ee,
                                                 Qn, Kn, Vn, out);
}